// Round 6
// baseline (227.828 us; speedup 1.0000x reference)
//
#include <hip/hip_runtime.h>

#define D 1024      // in_features
#define E 64        // num experts
#define TPB 512     // threads per block (8 waves)
#define TOKS 16     // tokens per block (one 16-row MFMA strip)
#define NW 8        // waves per block (K split 8 ways)
#define KSW 4       // k-steps per wave

// LDS A-tile geometry: 16 rows x 128 16B-slots (8 bf16 each) + 1 pad slot/row
#define SPR 129                 // slots per row (pad -> uniform bank spread)
#define ROWB (SPR * 16)         // 2064 bytes per row
#define TILEB (16 * ROWB)       // 33024 bytes per tile (hi or lo)

typedef __attribute__((ext_vector_type(8))) short bf16x8;
typedef __attribute__((ext_vector_type(8))) unsigned short u16x8;
typedef __attribute__((ext_vector_type(4))) float f32x4;
typedef __attribute__((ext_vector_type(4))) unsigned int u32x4;

__device__ __forceinline__ unsigned short bf16_rne(float f) {
    unsigned u = __builtin_bit_cast(unsigned, f);
    u += 0x7fffu + ((u >> 16) & 1u);
    return (unsigned short)(u >> 16);
}
__device__ __forceinline__ float bf16_to_f(unsigned short h) {
    unsigned u = ((unsigned)h) << 16;
    return __builtin_bit_cast(float, u);
}
__device__ __forceinline__ unsigned cvt_pk_bf16(float a, float b) {
    // dst[15:0]=bf16_rne(a), dst[31:16]=bf16_rne(b) — bit-identical to bf16_rne
    unsigned r;
    asm("v_cvt_pk_bf16_f32 %0, %1, %2" : "=v"(r) : "v"(a), "v"(b));
    return r;
}
__device__ __forceinline__ float lo_val(unsigned p) {
    return __builtin_bit_cast(float, p << 16);
}
__device__ __forceinline__ float hi_val(unsigned p) {
    return __builtin_bit_cast(float, p & 0xffff0000u);
}

struct Bfrag { bf16x8 f0, f1, f2, f3, f4, f5, f6, f7; };

// Split 8 fp32 into bf16 hi (RNE) + bf16 lo (RNE of exact residual).
// Bitwise-identical values to the original verified split_hi_lo scheme.
__device__ __forceinline__ void split8_rne(f32x4 a, f32x4 b, bf16x8& hv, bf16x8& lv) {
    unsigned h0 = cvt_pk_bf16(a[0], a[1]);
    unsigned h1 = cvt_pk_bf16(a[2], a[3]);
    unsigned h2 = cvt_pk_bf16(b[0], b[1]);
    unsigned h3 = cvt_pk_bf16(b[2], b[3]);
    unsigned l0 = cvt_pk_bf16(a[0] - lo_val(h0), a[1] - hi_val(h0));
    unsigned l1 = cvt_pk_bf16(a[2] - lo_val(h1), a[3] - hi_val(h1));
    unsigned l2 = cvt_pk_bf16(b[0] - lo_val(h2), b[1] - hi_val(h2));
    unsigned l3 = cvt_pk_bf16(b[2] - lo_val(h3), b[3] - hi_val(h3));
    hv = __builtin_bit_cast(bf16x8, (u32x4){h0, h1, h2, h3});
    lv = __builtin_bit_cast(bf16x8, (u32x4){l0, l1, l2, l3});
}

// ---------------------------------------------------------------------------
// One-time prep (unchanged, proven): W -> RNE hi/lo bf16 in MFMA B-fragment
// lane order.  Record f = (ks*4+nt)*2+hl, 64 lanes x 16B.  256 KB -> d_ws.
// ---------------------------------------------------------------------------
__global__ __launch_bounds__(256) void router_prep(
        const float* __restrict__ W, unsigned short* __restrict__ Ws) {
    int t = blockIdx.x * 256 + threadIdx.x;  // 0..8191
    int lane = t & 63;
    int nt = (t >> 6) & 3;
    int ks = t >> 8;
    int n = lane & 15, q = lane >> 4;
    const float* src = W + (size_t)(nt * 16 + n) * D + ks * 32 + q * 8;
    u16x8 hv, lv;
#pragma unroll
    for (int j = 0; j < 8; ++j) {
        float v = src[j];
        unsigned short h = bf16_rne(v);
        hv[j] = h;
        lv[j] = bf16_rne(v - bf16_to_f(h));
    }
    size_t base = ((size_t)(ks * 8 + nt * 2) * 64 + lane) * 8;
    *(u16x8*)(Ws + base)          = hv;      // hl = 0
    *(u16x8*)(Ws + base + 64 * 8) = lv;      // hl = 1
}

// ---------------------------------------------------------------------------
// Main.  The A path is the fix this round: every previous design loaded x
// with 16B/lane at 4KB lane stride (64 unique cache lines per instruction —
// TCP address-divergence wall, the invariant across all ~65-88us versions).
// Now: stage the 16x1024 x-tile into LDS with fully-coalesced loads, split
// to bf16 hi/lo ONCE at staging (same split values bitwise), and read MFMA
// fragments via ds_read_b128 (row pad -> uniform bank-group spread).
// B comes straight from L2 in prep's coalesced fragment order.
// 8 waves/block each own 4 k-steps; deterministic 8-way partial reduce.
// ---------------------------------------------------------------------------
__global__ __launch_bounds__(TPB, 4) void router_main(
        const float* __restrict__ x, const unsigned short* __restrict__ Ws,
        const float* __restrict__ bias, float* __restrict__ out, int T) {
    __shared__ __align__(16) union SM {
        unsigned char tile[2 * TILEB];                  // hi tile | lo tile (66 KB)
        struct { float part[NW][TOKS][E]; float ls[TOKS][E + 1]; } r;
    } sm;

    const int tid  = threadIdx.x;
    const int lane = tid & 63;
    const int wid  = tid >> 6;     // K-slice 0..7
    const int n    = lane & 15;
    const int q    = lane >> 4;
    const int t0   = blockIdx.x * TOKS;

    // ---- stage x-tile (16 tokens x 1024) -> LDS hi/lo, coalesced ----
    {
        const float* xt = x + (size_t)t0 * D;
#pragma unroll
        for (int i = 0; i < 4; ++i) {
            int j = tid + i * TPB;           // LDS slot 0..2047
            int row = j >> 7, col8 = j & 127;
            const float* g = xt + (size_t)row * D + col8 * 8;
            f32x4 a = *(const f32x4*)g;
            f32x4 b = *(const f32x4*)(g + 4);
            bf16x8 hv, lv;
            split8_rne(a, b, hv, lv);
            char* base = (char*)sm.tile + row * ROWB + col8 * 16;
            *(bf16x8*)base           = hv;
            *(bf16x8*)(base + TILEB) = lv;
        }
    }
    __syncthreads();

    f32x4 c0 = {0.f, 0.f, 0.f, 0.f}, c1 = c0, c2 = c0, c3 = c0;
    Bfrag Bt;
    const bf16x8* bptr = (const bf16x8*)Ws + lane;
    // lane's A base: row n, +q-th 16B slot; k-step ks adds ks*64 bytes
    const char* arow_h = (const char*)sm.tile + n * ROWB + q * 16;

#define LOADB(ks_) do {                                       \
        const bf16x8* _p = bptr + (size_t)(ks_) * 512;        \
        Bt.f0 = _p[0];   Bt.f1 = _p[64];  Bt.f2 = _p[128];    \
        Bt.f3 = _p[192]; Bt.f4 = _p[256]; Bt.f5 = _p[320];    \
        Bt.f6 = _p[384]; Bt.f7 = _p[448];                     \
    } while (0)

#define MFMA __builtin_amdgcn_mfma_f32_16x16x32_bf16
#define COMP(ah_, al_) do {                                   \
        c0 = MFMA(ah_, Bt.f0, c0, 0, 0, 0);                   \
        c0 = MFMA(al_, Bt.f0, c0, 0, 0, 0);                   \
        c0 = MFMA(ah_, Bt.f1, c0, 0, 0, 0);                   \
        c1 = MFMA(ah_, Bt.f2, c1, 0, 0, 0);                   \
        c1 = MFMA(al_, Bt.f2, c1, 0, 0, 0);                   \
        c1 = MFMA(ah_, Bt.f3, c1, 0, 0, 0);                   \
        c2 = MFMA(ah_, Bt.f4, c2, 0, 0, 0);                   \
        c2 = MFMA(al_, Bt.f4, c2, 0, 0, 0);                   \
        c2 = MFMA(ah_, Bt.f5, c2, 0, 0, 0);                   \
        c3 = MFMA(ah_, Bt.f6, c3, 0, 0, 0);                   \
        c3 = MFMA(al_, Bt.f6, c3, 0, 0, 0);                   \
        c3 = MFMA(ah_, Bt.f7, c3, 0, 0, 0);                   \
    } while (0)

#pragma unroll
    for (int kk = 0; kk < KSW; ++kk) {
        const int ks = (wid << 2) + kk;       // this wave's k-steps
        LOADB(ks);
        const char* p = arow_h + ks * 64;
        bf16x8 ah = *(const bf16x8*)p;
        bf16x8 al = *(const bf16x8*)(p + TILEB);
        COMP(ah, al);
    }

    // all waves must finish reading the tile before partials overwrite it
    __syncthreads();

    // partials: C/D layout col = lane&15 (expert base nt*16), row = q*4+r
    {
        const int row = q * 4;
#define STORE_P(c_, nt_) do {                                 \
            int col = (nt_) * 16 + n;                         \
            sm.r.part[wid][row + 0][col] = c_[0];             \
            sm.r.part[wid][row + 1][col] = c_[1];             \
            sm.r.part[wid][row + 2][col] = c_[2];             \
            sm.r.part[wid][row + 3][col] = c_[3];             \
        } while (0)
        STORE_P(c0, 0); STORE_P(c1, 1); STORE_P(c2, 2); STORE_P(c3, 3);
#undef STORE_P
    }
    __syncthreads();

    // deterministic 8-way reduce + bias: 1024 (token,expert) pairs, 2/thread
#pragma unroll
    for (int i = 0; i < 2; ++i) {
        int idx = tid + i * TPB;
        int tok = idx >> 6, e = idx & 63;
        float s = sm.r.part[0][tok][e];
        s += sm.r.part[1][tok][e];
        s += sm.r.part[2][tok][e];
        s += sm.r.part[3][tok][e];
        s += sm.r.part[4][tok][e];
        s += sm.r.part[5][tok][e];
        s += sm.r.part[6][tok][e];
        s += sm.r.part[7][tok][e];
        sm.r.ls[tok][e] = s + bias[e];
    }
    __syncthreads();

    if (tid < TOKS) {
        float m1 = -3.4e38f, m2 = -3.4e38f;
        int i1 = 0, i2 = 0;
        for (int e = 0; e < E; ++e) {
            float v = sm.r.ls[tid][e];
            if (v > m1) { m2 = m1; i2 = i1; m1 = v; i1 = e; }
            else if (v > m2) { m2 = v; i2 = e; }
        }
        float Z = 0.f;
        for (int e = 0; e < E; ++e) Z += __expf(sm.r.ls[tid][e] - m1);
        float inv = 1.f / Z;
        int gt = t0 + tid;
        out[(size_t)gt * 2]     = inv;                  // exp(m1-m1)/Z
        out[(size_t)gt * 2 + 1] = __expf(m2 - m1) * inv;
        float* oi = out + (size_t)T * 2;
        oi[(size_t)gt * 2]     = (float)i1;             // indices as floats
        oi[(size_t)gt * 2 + 1] = (float)i2;
    }
}

extern "C" void kernel_launch(void* const* d_in, const int* in_sizes, int n_in,
                              void* d_out, int out_size, void* d_ws, size_t ws_size,
                              hipStream_t stream) {
    const float* x = (const float*)d_in[0];
    const float* W = (const float*)d_in[1];
    const float* b = (const float*)d_in[2];
    float* out = (float*)d_out;
    unsigned short* Ws = (unsigned short*)d_ws;   // needs 256 KB
    int T = in_sizes[0] / D;                      // 32768 tokens
    hipLaunchKernelGGL(router_prep, dim3(32), dim3(256), 0, stream, W, Ws);
    hipLaunchKernelGGL(router_main, dim3(T / TOKS), dim3(TPB), 0, stream,
                       x, Ws, b, out, T);
}

// Round 8
// 203.987 us; speedup vs baseline: 1.1169x; 1.1169x over previous
//
#include <hip/hip_runtime.h>

#define D 1024      // in_features
#define E 64        // num experts
#define TPB 256     // threads per block (4 waves)
#define TOKS 64     // tokens per block (16 per wave)
#define NCH 8       // chunks of 128 k (4 MFMA k-steps) -> 8 barrier phases
#define CHB 32768   // bytes per staged W chunk (4 ks x 8 records x 1KB)

typedef __attribute__((ext_vector_type(8))) short bf16x8;
typedef __attribute__((ext_vector_type(8))) unsigned short u16x8;
typedef __attribute__((ext_vector_type(4))) float f32x4;
typedef __attribute__((ext_vector_type(4))) unsigned int u32x4;

__device__ __forceinline__ unsigned short bf16_rne(float f) {
    unsigned u = __builtin_bit_cast(unsigned, f);
    u += 0x7fffu + ((u >> 16) & 1u);
    return (unsigned short)(u >> 16);
}
__device__ __forceinline__ float bf16_to_f(unsigned short h) {
    unsigned u = ((unsigned)h) << 16;
    return __builtin_bit_cast(float, u);
}
__device__ __forceinline__ unsigned cvt_pk_bf16(float a, float b) {
    // dst[15:0]=bf16_rne(a), dst[31:16]=bf16_rne(b) — bit-identical to bf16_rne
    unsigned r;
    asm("v_cvt_pk_bf16_f32 %0, %1, %2" : "=v"(r) : "v"(a), "v"(b));
    return r;
}
__device__ __forceinline__ float lo_val(unsigned p) {
    return __builtin_bit_cast(float, p << 16);
}
__device__ __forceinline__ float hi_val(unsigned p) {
    return __builtin_bit_cast(float, p & 0xffff0000u);
}

// Split 8 fp32 into bf16 hi (RNE) + bf16 lo (RNE of exact residual).
// Bitwise-identical values to the original verified split_hi_lo scheme.
__device__ __forceinline__ void split8_rne(f32x4 a, f32x4 b, bf16x8& hv, bf16x8& lv) {
    unsigned h0 = cvt_pk_bf16(a[0], a[1]);
    unsigned h1 = cvt_pk_bf16(a[2], a[3]);
    unsigned h2 = cvt_pk_bf16(b[0], b[1]);
    unsigned h3 = cvt_pk_bf16(b[2], b[3]);
    unsigned l0 = cvt_pk_bf16(a[0] - lo_val(h0), a[1] - hi_val(h0));
    unsigned l1 = cvt_pk_bf16(a[2] - lo_val(h1), a[3] - hi_val(h1));
    unsigned l2 = cvt_pk_bf16(b[0] - lo_val(h2), b[1] - hi_val(h2));
    unsigned l3 = cvt_pk_bf16(b[2] - lo_val(h3), b[3] - hi_val(h3));
    hv = __builtin_bit_cast(bf16x8, (u32x4){h0, h1, h2, h3});
    lv = __builtin_bit_cast(bf16x8, (u32x4){l0, l1, l2, l3});
}

// ---------------------------------------------------------------------------
// One-time prep (proven): W -> RNE hi/lo bf16 in MFMA B-fragment lane order.
// Record f = (ks*8 + nt*2 + hl): 64 lanes x 16B; lane (n,q) holds
// W[nt*16+n][ks*32 + q*8 + 0..7].  256 KB -> d_ws.
// ---------------------------------------------------------------------------
__global__ __launch_bounds__(256) void router_prep(
        const float* __restrict__ W, unsigned short* __restrict__ Ws) {
    int t = blockIdx.x * 256 + threadIdx.x;  // 0..8191
    int lane = t & 63;
    int nt = (t >> 6) & 3;
    int ks = t >> 8;
    int n = lane & 15, q = lane >> 4;
    const float* src = W + (size_t)(nt * 16 + n) * D + ks * 32 + q * 8;
    u16x8 hv, lv;
#pragma unroll
    for (int j = 0; j < 8; ++j) {
        float v = src[j];
        unsigned short h = bf16_rne(v);
        hv[j] = h;
        lv[j] = bf16_rne(v - bf16_to_f(h));
    }
    size_t base = ((size_t)(ks * 8 + nt * 2) * 64 + lane) * 8;
    *(u16x8*)(Ws + base)          = hv;      // hl = 0
    *(u16x8*)(Ws + base + 64 * 8) = lv;      // hl = 1
}

// ---------------------------------------------------------------------------
// Main: baseline skeleton (barrier-batched phases — the only structure that
// survived 6 rounds), with 8x fewer barrier-drains and zero W-split VALU.
// 8 chunks x 128 k; per chunk: issue next chunk's W+A global loads EARLY,
// compute current chunk from LDS (double-buffered), write the W batch to the
// other LDS buffer LATE, one barrier.  Loads are batched per phase and
// drained once at the barrier — robust to hipcc's load-sinking.
// ---------------------------------------------------------------------------
__global__ __launch_bounds__(TPB) void router_main(
        const float* __restrict__ x, const unsigned short* __restrict__ Ws,
        const float* __restrict__ bias, float* __restrict__ out, int T) {
    __shared__ __align__(16) union SM {
        unsigned char buf[2][CHB];          // 64 KB: double-buffered W chunks
        float ls[TOKS][E + 1];              // epilogue logits (union reuse)
    } sm;
    __shared__ float sbias[E];

    const int tid  = threadIdx.x;
    const int lane = tid & 63;
    const int wid  = tid >> 6;
    const int n    = lane & 15;
    const int q    = lane >> 4;
    const int t0   = blockIdx.x * TOKS;

    if (tid < E) sbias[tid] = bias[tid];

    const float* arow = x + (size_t)(t0 + wid * 16 + n) * D + q * 8;
    const u32x4* gws  = (const u32x4*)Ws;

    f32x4 c0 = {0.f, 0.f, 0.f, 0.f}, c1 = c0, c2 = c0, c3 = c0;

    // Named register batches only (rule #20).
    u32x4 W0, W1, W2, W3, W4, W5, W6, W7;                 // staged W chunk
    f32x4 A0u, A0v, A1u, A1v, A2u, A2v, A3u, A3v;         // A chunk (cur)
    f32x4 N0u, N0v, N1u, N1v, N2u, N2v, N3u, N3v;         // A chunk (next)

#define ISSUEW(c_) do {                                               \
        const u32x4* _g = gws + (size_t)(c_) * 2048 + tid;            \
        W0 = _g[0];    W1 = _g[256];  W2 = _g[512];  W3 = _g[768];    \
        W4 = _g[1024]; W5 = _g[1280]; W6 = _g[1536]; W7 = _g[1792];   \
    } while (0)

#define WRITEW(bi_) do {                                              \
        u32x4* _l = (u32x4*)sm.buf[bi_] + tid;                        \
        _l[0]    = W0; _l[256]  = W1; _l[512]  = W2; _l[768]  = W3;   \
        _l[1024] = W4; _l[1280] = W5; _l[1536] = W6; _l[1792] = W7;   \
    } while (0)

#define ISSUEA(p0u,p0v,p1u,p1v,p2u,p2v,p3u,p3v, c_) do {              \
        const float* _b = arow + (size_t)(c_) * 128;                  \
        p0u = *(const f32x4*)(_b);       p0v = *(const f32x4*)(_b + 4);   \
        p1u = *(const f32x4*)(_b + 32);  p1v = *(const f32x4*)(_b + 36);  \
        p2u = *(const f32x4*)(_b + 64);  p2v = *(const f32x4*)(_b + 68);  \
        p3u = *(const f32x4*)(_b + 96);  p3v = *(const f32x4*)(_b + 100); \
    } while (0)

#define MFMA __builtin_amdgcn_mfma_f32_16x16x32_bf16
// One MFMA k-step: A pair (au,av) against the 8 frag-records of k-step ksl.
// Accumulation order identical to all passing rounds: per nt (ah,bh),(al,bh),(ah,bl).
#define COMPSTEP(bi_, ksl_, au_, av_) do {                            \
        bf16x8 ah, al;                                                \
        split8_rne(au_, av_, ah, al);                                 \
        const char* _p = (const char*)sm.buf[bi_] + (ksl_) * 8192 + lane * 16; \
        {                                                             \
            bf16x8 bh = *(const bf16x8*)(_p);                         \
            bf16x8 bl = *(const bf16x8*)(_p + 1024);                  \
            c0 = MFMA(ah, bh, c0, 0, 0, 0);                           \
            c0 = MFMA(al, bh, c0, 0, 0, 0);                           \
            c0 = MFMA(ah, bl, c0, 0, 0, 0);                           \
        }                                                             \
        {                                                             \
            bf16x8 bh = *(const bf16x8*)(_p + 2048);                  \
            bf16x8 bl = *(const bf16x8*)(_p + 3072);                  \
            c1 = MFMA(ah, bh, c1, 0, 0, 0);                           \
            c1 = MFMA(al, bh, c1, 0, 0, 0);                           \
            c1 = MFMA(ah, bl, c1, 0, 0, 0);                           \
        }                                                             \
        {                                                             \
            bf16x8 bh = *(const bf16x8*)(_p + 4096);                  \
            bf16x8 bl = *(const bf16x8*)(_p + 5120);                  \
            c2 = MFMA(ah, bh, c2, 0, 0, 0);                           \
            c2 = MFMA(al, bh, c2, 0, 0, 0);                           \
            c2 = MFMA(ah, bl, c2, 0, 0, 0);                           \
        }                                                             \
        {                                                             \
            bf16x8 bh = *(const bf16x8*)(_p + 6144);                  \
            bf16x8 bl = *(const bf16x8*)(_p + 7168);                  \
            c3 = MFMA(ah, bh, c3, 0, 0, 0);                           \
            c3 = MFMA(al, bh, c3, 0, 0, 0);                           \
            c3 = MFMA(ah, bl, c3, 0, 0, 0);                           \
        }                                                             \
    } while (0)

#define COMPCHUNK(bi_, p0u,p0v,p1u,p1v,p2u,p2v,p3u,p3v) do {          \
        COMPSTEP(bi_, 0, p0u, p0v);                                   \
        COMPSTEP(bi_, 1, p1u, p1v);                                   \
        COMPSTEP(bi_, 2, p2u, p2v);                                   \
        COMPSTEP(bi_, 3, p3u, p3v);                                   \
    } while (0)

    // ---- prologue: chunk 0 into buf0, A chunk 0 into regs ----
    ISSUEW(0);
    ISSUEA(A0u,A0v,A1u,A1v,A2u,A2v,A3u,A3v, 0);
    WRITEW(0);
    __syncthreads();

    // ---- 8 phases, one barrier each; manual 2x unroll keeps names static ----
    for (int c = 0; c < NCH; c += 2) {
        // even chunk c: compute buf0, prefetch chunk c+1
        ISSUEW(c + 1);
        ISSUEA(N0u,N0v,N1u,N1v,N2u,N2v,N3u,N3v, c + 1);
        COMPCHUNK(0, A0u,A0v,A1u,A1v,A2u,A2v,A3u,A3v);
        WRITEW(1);
        __syncthreads();
        // odd chunk c+1: compute buf1, prefetch chunk c+2 (wrap harmless)
        ISSUEW((c + 2) & (NCH - 1));
        ISSUEA(A0u,A0v,A1u,A1v,A2u,A2v,A3u,A3v, (c + 2) & (NCH - 1));
        COMPCHUNK(1, N0u,N0v,N1u,N1v,N2u,N2v,N3u,N3v);
        WRITEW(0);
        __syncthreads();
    }

    // ---- epilogue: logits (+bias) into union'd LDS, softmax + top-2 ----
    {
        const int row = wid * 16 + q * 4;
#define STORE_C(c_, nt_) do {                                         \
            int col = (nt_) * 16 + n;                                 \
            float bv = sbias[col];                                    \
            sm.ls[row + 0][col] = c_[0] + bv;                         \
            sm.ls[row + 1][col] = c_[1] + bv;                         \
            sm.ls[row + 2][col] = c_[2] + bv;                         \
            sm.ls[row + 3][col] = c_[3] + bv;                         \
        } while (0)
        STORE_C(c0, 0); STORE_C(c1, 1); STORE_C(c2, 2); STORE_C(c3, 3);
#undef STORE_C
    }
    __syncthreads();

    if (tid < TOKS) {
        float m1 = -3.4e38f, m2 = -3.4e38f;
        int i1 = 0, i2 = 0;
        for (int e = 0; e < E; ++e) {
            float v = sm.ls[tid][e];
            if (v > m1) { m2 = m1; i2 = i1; m1 = v; i1 = e; }
            else if (v > m2) { m2 = v; i2 = e; }
        }
        float Z = 0.f;
        for (int e = 0; e < E; ++e) Z += __expf(sm.ls[tid][e] - m1);
        float inv = 1.f / Z;
        int gt = t0 + tid;
        out[(size_t)gt * 2]     = inv;                  // exp(m1-m1)/Z
        out[(size_t)gt * 2 + 1] = __expf(m2 - m1) * inv;
        float* oi = out + (size_t)T * 2;
        oi[(size_t)gt * 2]     = (float)i1;             // indices as floats
        oi[(size_t)gt * 2 + 1] = (float)i2;
    }
}

extern "C" void kernel_launch(void* const* d_in, const int* in_sizes, int n_in,
                              void* d_out, int out_size, void* d_ws, size_t ws_size,
                              hipStream_t stream) {
    const float* x = (const float*)d_in[0];
    const float* W = (const float*)d_in[1];
    const float* b = (const float*)d_in[2];
    float* out = (float*)d_out;
    unsigned short* Ws = (unsigned short*)d_ws;   // needs 256 KB
    int T = in_sizes[0] / D;                      // 32768 tokens
    hipLaunchKernelGGL(router_prep, dim3(32), dim3(256), 0, stream, W, Ws);
    hipLaunchKernelGGL(router_main, dim3(T / TOKS), dim3(TPB), 0, stream,
                       x, Ws, b, out, T);
}